// Round 2
// baseline (825.142 us; speedup 1.0000x reference)
//
#include <hip/hip_runtime.h>
#include <hip/hip_bf16.h>

// ---------------------------------------------------------------------------
// Bahdanau attention, fused flash-style.  B=64, S=2048, E=D=U=512.
//  K1: pack W1 (fp32) -> bf16 in MFMA B-fragment order (ws)
//  K2: c[b,u] = H@W2 + b1 + b2   (fp32, ws)
//  K3: scores_ctx: per (b, 128-row strip):
//        raw score s = tanh(EO@W1 + c)·V      (bf16 MFMA, A-frags in regs,
//                                              B double-buffered in LDS)
//        strip softmax partials m,l and partial context Sum exp(s-m)*EO
//        (EO taken from the bf16 A-fragments still in registers)
//  K4: combine: M,L per b; context = rescaled partial sum; weights =
//        exp(score-M)/L written over the raw scores.   (bv is softmax-shift
//        invariant -> dropped entirely.)
// d_out layout: context [64*512] then weights [64*2048].
// ws: W1p 512K | cvec 128K | m 4K | l 4K | ck 2M   (~2.75 MB)
// ---------------------------------------------------------------------------

typedef __attribute__((ext_vector_type(8))) short bf16x8;   // 8 bf16 = 4 VGPR
typedef __attribute__((ext_vector_type(4))) float f32x4;

#define NB 64
#define NS 2048
#define NE 512
#define NU 512

__device__ __forceinline__ unsigned short f2bf(float f) {
  union { float f; unsigned int u; } x; x.f = f;
  unsigned int u = x.u;
  unsigned int r = (u + 0x7fffu + ((u >> 16) & 1u)) >> 16;  // RNE
  return (unsigned short)r;
}

__device__ __forceinline__ float bf2f(short s) {
  union { unsigned int u; float f; } x;
  x.u = ((unsigned int)(unsigned short)s) << 16;
  return x.f;
}

__device__ __forceinline__ float tanh_fast(float x) {
  x = fminf(fmaxf(x, -15.f), 15.f);
  float e = __expf(2.f * x);
  return 1.f - 2.f / (e + 1.f);
}

// --- K1: pack W1[k][n] (fp32 512x512) -> bf16 MFMA B-frag order:
//     W1p[(((nt*16+kt)*64 + lane)*8 + j)] = bf16(W1[kt*32+(lane>>4)*8+j][nt*16+(lane&15)])
__global__ __launch_bounds__(256) void pack_w1_kernel(
    const float* __restrict__ W1, unsigned short* __restrict__ W1p) {
  int t = blockIdx.x * 256 + threadIdx.x;
  int k = t >> 9, n = t & 511;
  int kt = k >> 5, kr = k & 31;
  int quad = kr >> 3, j = kr & 7;
  int l = (quad << 4) | (n & 15);
  int nt = n >> 4;
  int dst = ((((nt << 4) + kt) * 64 + l) << 3) + j;
  W1p[dst] = f2bf(W1[t]);
}

// --- K2: c[b][u] = sum_d H[b][d]*W2[d][u] + b1[u] + b2[u]
__global__ __launch_bounds__(512) void compute_c_kernel(
    const float* __restrict__ H, const float* __restrict__ W2,
    const float* __restrict__ b1, const float* __restrict__ b2,
    float* __restrict__ cvec) {
  const int b = blockIdx.x, u = threadIdx.x;
  __shared__ float hs[512];
  hs[u] = H[(b << 9) + u];
  __syncthreads();
  float s = 0.f;
#pragma unroll 8
  for (int d = 0; d < 512; d++) s = fmaf(hs[d], W2[(d << 9) + u], s);
  cvec[(b << 9) + u] = s + b1[u] + b2[u];
}

// --- K3: scores + softmax partials + context partials.
// grid 1024 (= 64 b * 16 strips), 256 thr (4 waves), 2 blocks/CU.
__global__ __launch_bounds__(256, 2) void scores_ctx_kernel(
    const float* __restrict__ EO, const unsigned short* __restrict__ W1p,
    const float* __restrict__ cvec, const float* __restrict__ V,
    float* __restrict__ scores, float* __restrict__ m_ws,
    float* __restrict__ l_ws, float* __restrict__ ck_ws) {
  __shared__ __align__(16) unsigned short Bs[2][16384];  // 2 x 32KB (2 nt each)
  __shared__ float cs[512], vs[512];
  __shared__ float sc_l[128], p_l[128];
  __shared__ __align__(16) float cpartw[4][512];
  __shared__ float m_sh, lw[2];

  const int tid = threadIdx.x;
  const int b = blockIdx.x >> 4;
  const int strip = blockIdx.x & 15;
  const int s0 = strip << 7;
  const int lane = tid & 63, wave = tid >> 6;
  const int quad = lane >> 4, col = lane & 15;

  cs[tid] = cvec[(b << 9) + tid];
  cs[tid + 256] = cvec[(b << 9) + 256 + tid];
  vs[tid] = V[tid];
  vs[tid + 256] = V[256 + tid];

  // ---- A-fragments straight from global (128B segments, fully used),
  //      fp32 -> bf16 in registers.  No LDS copy exists -> must stay in VGPRs.
  bf16x8 afrag[2][16];  // [row-tile][kt] : 128 VGPRs
  {
    const float* r0 =
        EO + ((size_t)(b * NS + s0 + wave * 32 + col)) * NE + quad * 8;
    const float* r1 = r0 + 16 * NE;
#pragma unroll
    for (int kt = 0; kt < 16; kt++) {
      float4 x0 = *(const float4*)(r0 + kt * 32);
      float4 y0 = *(const float4*)(r0 + kt * 32 + 4);
      float4 x1 = *(const float4*)(r1 + kt * 32);
      float4 y1 = *(const float4*)(r1 + kt * 32 + 4);
      union { short s[8]; bf16x8 v; } u0, u1;
      u0.s[0] = (short)f2bf(x0.x); u0.s[1] = (short)f2bf(x0.y);
      u0.s[2] = (short)f2bf(x0.z); u0.s[3] = (short)f2bf(x0.w);
      u0.s[4] = (short)f2bf(y0.x); u0.s[5] = (short)f2bf(y0.y);
      u0.s[6] = (short)f2bf(y0.z); u0.s[7] = (short)f2bf(y0.w);
      u1.s[0] = (short)f2bf(x1.x); u1.s[1] = (short)f2bf(x1.y);
      u1.s[2] = (short)f2bf(x1.z); u1.s[3] = (short)f2bf(x1.w);
      u1.s[4] = (short)f2bf(y1.x); u1.s[5] = (short)f2bf(y1.y);
      u1.s[6] = (short)f2bf(y1.z); u1.s[7] = (short)f2bf(y1.w);
      afrag[0][kt] = u0.v;
      afrag[1][kt] = u1.v;
    }
  }

  const uint4* W1p4 = (const uint4*)W1p;  // 32KB tile = 2048 uint4
  // ---- stage B tile 0 (nt 0,1)
#pragma unroll
  for (int i = 0; i < 8; i++)
    ((uint4*)&Bs[0][0])[i * 256 + tid] = W1p4[i * 256 + tid];
  __syncthreads();

  float sacc[2][4] = {{0.f, 0.f, 0.f, 0.f}, {0.f, 0.f, 0.f, 0.f}};

  for (int it = 0; it < 16; it++) {
    const int cur = it & 1;
    uint4 breg[8];
    if (it < 15) {
#pragma unroll
      for (int i = 0; i < 8; i++)
        breg[i] = W1p4[(it + 1) * 2048 + i * 256 + tid];
    }
#pragma unroll
    for (int half = 0; half < 2; half++) {
      const int nt = it * 2 + half;
      f32x4 acc0 = {0.f, 0.f, 0.f, 0.f};
      f32x4 acc1 = {0.f, 0.f, 0.f, 0.f};
      const bf16x8* bp = (const bf16x8*)&Bs[cur][half * 8192];
#pragma unroll
      for (int kt = 0; kt < 16; kt++) {
        bf16x8 bfr = bp[kt * 64 + lane];
        acc0 = __builtin_amdgcn_mfma_f32_16x16x32_bf16(afrag[0][kt], bfr, acc0, 0, 0, 0);
        acc1 = __builtin_amdgcn_mfma_f32_16x16x32_bf16(afrag[1][kt], bfr, acc1, 0, 0, 0);
      }
      // fused epilogue: score partial += tanh(acc + c[u]) * V[u]
      int u = (nt << 4) + col;
      float cu = cs[u], vu = vs[u];
#pragma unroll
      for (int r = 0; r < 4; r++) {
        sacc[0][r] += tanh_fast(acc0[r] + cu) * vu;
        sacc[1][r] += tanh_fast(acc1[r] + cu) * vu;
      }
    }
    if (it < 15) {
#pragma unroll
      for (int i = 0; i < 8; i++)
        ((uint4*)&Bs[cur ^ 1][0])[i * 256 + tid] = breg[i];
    }
    __syncthreads();
  }

  // ---- reduce scores over the 16 col-lanes of each quad-group
#pragma unroll
  for (int m = 1; m < 16; m <<= 1)
#pragma unroll
    for (int t = 0; t < 2; t++)
#pragma unroll
      for (int r = 0; r < 4; r++)
        sacc[t][r] += __shfl_xor(sacc[t][r], m, 64);

  if (col == 0) {
#pragma unroll
    for (int t = 0; t < 2; t++)
#pragma unroll
      for (int r = 0; r < 4; r++) {
        int row = wave * 32 + t * 16 + quad * 4 + r;
        sc_l[row] = sacc[t][r];
        scores[(size_t)b * NS + s0 + row] = sacc[t][r];  // raw scores
      }
  }
  __syncthreads();

  // ---- strip max
  if (wave == 0) {
    float m0 = fmaxf(sc_l[lane], sc_l[lane + 64]);
#pragma unroll
    for (int off = 32; off; off >>= 1) m0 = fmaxf(m0, __shfl_xor(m0, off, 64));
    if (lane == 0) m_sh = m0;
  }
  __syncthreads();
  const float mstrip = m_sh;

  // ---- p = exp(s - m), strip l
  if (tid < 128) {
    float p = __expf(sc_l[tid] - mstrip);
    p_l[tid] = p;
#pragma unroll
    for (int off = 32; off; off >>= 1) p += __shfl_xor(p, off, 64);
    if (lane == 0) lw[wave] = p;
  }
  __syncthreads();
  if (tid == 0) {
    m_ws[b * 16 + strip] = mstrip;
    l_ws[b * 16 + strip] = lw[0] + lw[1];
  }

  // ---- context partials from register-resident bf16 EO fragments.
  // lane holds rows (wave*32 + t*16 + col), e = kt*32 + quad*8 + j.
  const float p0 = p_l[wave * 32 + col];
  const float p1 = p_l[wave * 32 + 16 + col];
#pragma unroll
  for (int kt = 0; kt < 16; kt++) {
    float v[8];
#pragma unroll
    for (int j = 0; j < 8; j++)
      v[j] = p0 * bf2f(afrag[0][kt][j]) + p1 * bf2f(afrag[1][kt][j]);
#pragma unroll
    for (int m = 1; m < 16; m <<= 1)
#pragma unroll
      for (int j = 0; j < 8; j++) v[j] += __shfl_xor(v[j], m, 64);
    if (col == 0) {
      float* dst = &cpartw[wave][kt * 32 + quad * 8];
      *(float4*)dst = make_float4(v[0], v[1], v[2], v[3]);
      *(float4*)(dst + 4) = make_float4(v[4], v[5], v[6], v[7]);
    }
  }
  __syncthreads();

  // ---- fold 4 wave-partials, write strip context partial to ws
  {
    float2 s = {0.f, 0.f};
#pragma unroll
    for (int w = 0; w < 4; w++) {
      float2 t = *(const float2*)&cpartw[w][tid * 2];
      s.x += t.x; s.y += t.y;
    }
    *(float2*)&ck_ws[((size_t)(b * 16 + strip)) * 512 + tid * 2] = s;
  }
}

// --- K4: combine strips: context + normalized weights.  64 blocks x 256 thr.
__global__ __launch_bounds__(256) void combine_kernel(
    const float* __restrict__ m_ws, const float* __restrict__ l_ws,
    const float* __restrict__ ck_ws, float* __restrict__ ctx,
    float* __restrict__ w /* raw scores in, weights out */) {
  const int b = blockIdx.x, tid = threadIdx.x;
  __shared__ float msh[16], lsh[16];
  if (tid < 16) {
    msh[tid] = m_ws[b * 16 + tid];
    lsh[tid] = l_ws[b * 16 + tid];
  }
  __syncthreads();
  float M = msh[0];
#pragma unroll
  for (int k = 1; k < 16; k++) M = fmaxf(M, msh[k]);
  float L = 0.f;
#pragma unroll
  for (int k = 0; k < 16; k++) L += lsh[k] * __expf(msh[k] - M);
  const float invL = 1.f / L;

  float2 acc = {0.f, 0.f};
#pragma unroll
  for (int k = 0; k < 16; k++) {
    float sc = __expf(msh[k] - M);
    float2 t = *(const float2*)&ck_ws[((size_t)(b * 16 + k)) * 512 + tid * 2];
    acc.x += sc * t.x; acc.y += sc * t.y;
  }
  acc.x *= invL; acc.y *= invL;
  *(float2*)&ctx[(b << 9) + tid * 2] = acc;

  float* row = w + (size_t)b * NS;
#pragma unroll
  for (int i = 0; i < 8; i++) {
    float s = row[i * 256 + tid];
    row[i * 256 + tid] = __expf(s - M) * invL;
  }
}

extern "C" void kernel_launch(void* const* d_in, const int* in_sizes, int n_in,
                              void* d_out, int out_size, void* d_ws, size_t ws_size,
                              hipStream_t stream) {
  (void)in_sizes; (void)n_in; (void)out_size; (void)ws_size;
  const float* H  = (const float*)d_in[0];
  const float* EO = (const float*)d_in[1];
  const float* W1 = (const float*)d_in[2];
  const float* b1 = (const float*)d_in[3];
  const float* W2 = (const float*)d_in[4];
  const float* b2 = (const float*)d_in[5];
  const float* V  = (const float*)d_in[6];
  // d_in[7] = bv: softmax is shift-invariant -> unused.

  float* out_ctx = (float*)d_out;            // [64*512]
  float* out_w   = (float*)d_out + NB * NE;  // [64*2048] raw scores -> weights

  char* ws = (char*)d_ws;
  unsigned short* W1p = (unsigned short*)ws;            // 512 KB
  float* cvec = (float*)(ws + 512 * 1024);              // 128 KB
  float* m_ws = (float*)(ws + 640 * 1024);              // 4 KB
  float* l_ws = (float*)(ws + 644 * 1024);              // 4 KB
  float* ck_ws = (float*)(ws + 656 * 1024);             // 2 MB

  pack_w1_kernel<<<1024, 256, 0, stream>>>(W1, W1p);
  compute_c_kernel<<<NB, 512, 0, stream>>>(H, W2, b1, b2, cvec);
  scores_ctx_kernel<<<1024, 256, 0, stream>>>(EO, W1p, cvec, V, out_w,
                                              m_ws, l_ws, ck_ws);
  combine_kernel<<<NB, 256, 0, stream>>>(m_ws, l_ws, ck_ws, out_ctx, out_w);
}

// Round 3
// 665.640 us; speedup vs baseline: 1.2396x; 1.2396x over previous
//
#include <hip/hip_runtime.h>
#include <hip/hip_bf16.h>

// ---------------------------------------------------------------------------
// Bahdanau attention, fused flash-style.  B=64, S=2048, E=D=U=512.
//  K1: pack W1 (fp32) -> bf16 in MFMA B-fragment order (ws)
//  K2: c[b,u] = H@W2 + b1 + b2   (fp32, ws)
//  K3: scores_ctx: per (b, 128-row strip):
//        raw score s = tanh(EO@W1 + c)·V      (bf16 MFMA, A-frags in regs,
//        B double-buffered in LDS via global_load_lds DMA — no staging VGPRs)
//        strip softmax partials m,l and partial context Sum exp(s-m)*EO
//        (EO taken from the bf16 A-fragments still in registers)
//  K4: combine: M,L per b; context = rescaled partials; weights = exp(s-M)/L.
// d_out layout: context [64*512] then weights [64*2048].
// ws: W1p 512K | cvec 128K | m 4K | l 4K | ck 2M   (~2.75 MB)
// ---------------------------------------------------------------------------

typedef __attribute__((ext_vector_type(8))) short bf16x8;   // 8 bf16 = 4 VGPR
typedef __attribute__((ext_vector_type(4))) float f32x4;

#define NB 64
#define NS 2048
#define NE 512
#define NU 512

// async 16B/lane global->LDS DMA: lds dest = wave-uniform base + lane*16
#define ASYNC_CP16(gsrc, ldst)                                               \
  __builtin_amdgcn_global_load_lds(                                          \
      (const __attribute__((address_space(1))) unsigned int*)(gsrc),         \
      (__attribute__((address_space(3))) unsigned int*)(ldst), 16, 0, 0)

__device__ __forceinline__ unsigned short f2bf(float f) {
  union { float f; unsigned int u; } x; x.f = f;
  unsigned int u = x.u;
  unsigned int r = (u + 0x7fffu + ((u >> 16) & 1u)) >> 16;  // RNE
  return (unsigned short)r;
}

__device__ __forceinline__ float bf2f(short s) {
  union { unsigned int u; float f; } x;
  x.u = ((unsigned int)(unsigned short)s) << 16;
  return x.f;
}

__device__ __forceinline__ float tanh_fast(float x) {
  x = fminf(fmaxf(x, -15.f), 15.f);
  float e = __expf(2.f * x);
  return 1.f - 2.f / (e + 1.f);
}

// --- K1: pack W1[k][n] (fp32 512x512) -> bf16 MFMA B-frag order:
//     W1p[(((nt*16+kt)*64 + lane)*8 + j)] = bf16(W1[kt*32+(lane>>4)*8+j][nt*16+(lane&15)])
__global__ __launch_bounds__(256) void pack_w1_kernel(
    const float* __restrict__ W1, unsigned short* __restrict__ W1p) {
  int t = blockIdx.x * 256 + threadIdx.x;
  int k = t >> 9, n = t & 511;
  int kt = k >> 5, kr = k & 31;
  int quad = kr >> 3, j = kr & 7;
  int l = (quad << 4) | (n & 15);
  int nt = n >> 4;
  int dst = ((((nt << 4) + kt) * 64 + l) << 3) + j;
  W1p[dst] = f2bf(W1[t]);
}

// --- K2: c[b][u] = sum_d H[b][d]*W2[d][u] + b1[u] + b2[u]
__global__ __launch_bounds__(512) void compute_c_kernel(
    const float* __restrict__ H, const float* __restrict__ W2,
    const float* __restrict__ b1, const float* __restrict__ b2,
    float* __restrict__ cvec) {
  const int b = blockIdx.x, u = threadIdx.x;
  __shared__ float hs[512];
  hs[u] = H[(b << 9) + u];
  __syncthreads();
  float s = 0.f;
#pragma unroll 8
  for (int d = 0; d < 512; d++) s = fmaf(hs[d], W2[(d << 9) + u], s);
  cvec[(b << 9) + u] = s + b1[u] + b2[u];
}

// --- K3: scores + softmax partials + context partials.
// grid 1024 (= 64 b * 16 strips), 256 thr (4 waves), 2 blocks/CU (LDS 77KB).
__global__ __launch_bounds__(256)
__attribute__((amdgpu_waves_per_eu(2, 2)))
void scores_ctx_kernel(
    const float* __restrict__ EO, const unsigned short* __restrict__ W1p,
    const float* __restrict__ cvec, const float* __restrict__ V,
    float* __restrict__ scores, float* __restrict__ m_ws,
    float* __restrict__ l_ws, float* __restrict__ ck_ws) {
  __shared__ __align__(16) unsigned short Bs[2][16384];  // 2 x 32KB (2 nt each)
  __shared__ float cs[512], vs[512];
  __shared__ float sc_l[128], p_l[128];
  __shared__ __align__(16) float cpartw[4][512];
  __shared__ float m_sh, lw[2];

  const int tid = threadIdx.x;
  const int b = blockIdx.x >> 4;
  const int strip = blockIdx.x & 15;
  const int s0 = strip << 7;
  const int lane = tid & 63, wave = tid >> 6;
  const int quad = lane >> 4, col = lane & 15;

  const uint4* W1p4 = (const uint4*)W1p;  // one 32KB tile = 2048 uint4

  // ---- kick off DMA of B tile 0 (no VGPRs consumed)
#pragma unroll
  for (int i = 0; i < 8; i++)
    ASYNC_CP16(W1p4 + i * 256 + wave * 64 + lane,
               ((char*)&Bs[0][0]) + (i * 256 + wave * 64) * 16);

  cs[tid] = cvec[(b << 9) + tid];
  cs[tid + 256] = cvec[(b << 9) + 256 + tid];
  vs[tid] = V[tid];
  vs[tid + 256] = V[256 + tid];

  // ---- A-fragments straight from global (contiguous 32B/lane pieces,
  //      16 rows x 128B per instruction), fp32 -> bf16 in registers.
  bf16x8 afrag[2][16];  // [row-tile][kt] : 128 VGPRs
  {
    const float* r0 =
        EO + ((size_t)(b * NS + s0 + wave * 32 + col)) * NE + quad * 8;
    const float* r1 = r0 + 16 * NE;
#pragma unroll
    for (int kt = 0; kt < 16; kt++) {
      float4 x0 = *(const float4*)(r0 + kt * 32);
      float4 y0 = *(const float4*)(r0 + kt * 32 + 4);
      float4 x1 = *(const float4*)(r1 + kt * 32);
      float4 y1 = *(const float4*)(r1 + kt * 32 + 4);
      union { short s[8]; bf16x8 v; } u0, u1;
      u0.s[0] = (short)f2bf(x0.x); u0.s[1] = (short)f2bf(x0.y);
      u0.s[2] = (short)f2bf(x0.z); u0.s[3] = (short)f2bf(x0.w);
      u0.s[4] = (short)f2bf(y0.x); u0.s[5] = (short)f2bf(y0.y);
      u0.s[6] = (short)f2bf(y0.z); u0.s[7] = (short)f2bf(y0.w);
      u1.s[0] = (short)f2bf(x1.x); u1.s[1] = (short)f2bf(x1.y);
      u1.s[2] = (short)f2bf(x1.z); u1.s[3] = (short)f2bf(x1.w);
      u1.s[4] = (short)f2bf(y1.x); u1.s[5] = (short)f2bf(y1.y);
      u1.s[6] = (short)f2bf(y1.z); u1.s[7] = (short)f2bf(y1.w);
      afrag[0][kt] = u0.v;
      afrag[1][kt] = u1.v;
    }
  }

  __syncthreads();  // drains DMA vmcnt -> tile 0 ready

  float sacc[2][4] = {{0.f, 0.f, 0.f, 0.f}, {0.f, 0.f, 0.f, 0.f}};

  for (int it = 0; it < 16; it++) {
    const int cur = it & 1;
    // DMA-prefetch next 32KB B tile into the other buffer (overlaps MFMAs)
    if (it < 15) {
#pragma unroll
      for (int i = 0; i < 8; i++)
        ASYNC_CP16(W1p4 + (it + 1) * 2048 + i * 256 + wave * 64 + lane,
                   ((char*)&Bs[cur ^ 1][0]) + (i * 256 + wave * 64) * 16);
    }
#pragma unroll
    for (int half = 0; half < 2; half++) {
      const int nt = it * 2 + half;
      f32x4 acc0 = {0.f, 0.f, 0.f, 0.f};
      f32x4 acc1 = {0.f, 0.f, 0.f, 0.f};
      const bf16x8* bp = (const bf16x8*)&Bs[cur][half * 8192];
#pragma unroll
      for (int kt = 0; kt < 16; kt++) {
        bf16x8 bfr = bp[kt * 64 + lane];
        acc0 = __builtin_amdgcn_mfma_f32_16x16x32_bf16(afrag[0][kt], bfr, acc0, 0, 0, 0);
        acc1 = __builtin_amdgcn_mfma_f32_16x16x32_bf16(afrag[1][kt], bfr, acc1, 0, 0, 0);
      }
      // fused epilogue: score partial += tanh(acc + c[u]) * V[u]
      int u = (nt << 4) + col;
      float cu = cs[u], vu = vs[u];
#pragma unroll
      for (int r = 0; r < 4; r++) {
        sacc[0][r] += tanh_fast(acc0[r] + cu) * vu;
        sacc[1][r] += tanh_fast(acc1[r] + cu) * vu;
      }
    }
    __syncthreads();  // drains DMA (next tile ready) + all reads of cur done
  }

  // ---- reduce scores over the 16 col-lanes of each quad-group
#pragma unroll
  for (int m = 1; m < 16; m <<= 1)
#pragma unroll
    for (int t = 0; t < 2; t++)
#pragma unroll
      for (int r = 0; r < 4; r++)
        sacc[t][r] += __shfl_xor(sacc[t][r], m, 64);

  if (col == 0) {
#pragma unroll
    for (int t = 0; t < 2; t++)
#pragma unroll
      for (int r = 0; r < 4; r++) {
        int row = wave * 32 + t * 16 + quad * 4 + r;
        sc_l[row] = sacc[t][r];
        scores[(size_t)b * NS + s0 + row] = sacc[t][r];  // raw scores
      }
  }
  __syncthreads();

  // ---- strip max
  if (wave == 0) {
    float m0 = fmaxf(sc_l[lane], sc_l[lane + 64]);
#pragma unroll
    for (int off = 32; off; off >>= 1) m0 = fmaxf(m0, __shfl_xor(m0, off, 64));
    if (lane == 0) m_sh = m0;
  }
  __syncthreads();
  const float mstrip = m_sh;

  // ---- p = exp(s - m), strip l
  if (tid < 128) {
    float p = __expf(sc_l[tid] - mstrip);
    p_l[tid] = p;
#pragma unroll
    for (int off = 32; off; off >>= 1) p += __shfl_xor(p, off, 64);
    if (lane == 0) lw[wave] = p;
  }
  __syncthreads();
  if (tid == 0) {
    m_ws[b * 16 + strip] = mstrip;
    l_ws[b * 16 + strip] = lw[0] + lw[1];
  }

  // ---- context partials from register-resident bf16 EO fragments.
  // lane holds rows (wave*32 + t*16 + col), e = kt*32 + quad*8 + j.
  const float p0 = p_l[wave * 32 + col];
  const float p1 = p_l[wave * 32 + 16 + col];
#pragma unroll
  for (int kt = 0; kt < 16; kt++) {
    float v[8];
#pragma unroll
    for (int j = 0; j < 8; j++)
      v[j] = p0 * bf2f(afrag[0][kt][j]) + p1 * bf2f(afrag[1][kt][j]);
#pragma unroll
    for (int m = 1; m < 16; m <<= 1)
#pragma unroll
      for (int j = 0; j < 8; j++) v[j] += __shfl_xor(v[j], m, 64);
    if (col == 0) {
      float* dst = &cpartw[wave][kt * 32 + quad * 8];
      *(float4*)dst = make_float4(v[0], v[1], v[2], v[3]);
      *(float4*)(dst + 4) = make_float4(v[4], v[5], v[6], v[7]);
    }
  }
  __syncthreads();

  // ---- fold 4 wave-partials, write strip context partial to ws
  {
    float2 s = {0.f, 0.f};
#pragma unroll
    for (int w = 0; w < 4; w++) {
      float2 t = *(const float2*)&cpartw[w][tid * 2];
      s.x += t.x; s.y += t.y;
    }
    *(float2*)&ck_ws[((size_t)(b * 16 + strip)) * 512 + tid * 2] = s;
  }
}

// --- K4: combine strips: context + normalized weights.  64 blocks x 256 thr.
__global__ __launch_bounds__(256) void combine_kernel(
    const float* __restrict__ m_ws, const float* __restrict__ l_ws,
    const float* __restrict__ ck_ws, float* __restrict__ ctx,
    float* __restrict__ w /* raw scores in, weights out */) {
  const int b = blockIdx.x, tid = threadIdx.x;
  __shared__ float msh[16], lsh[16];
  if (tid < 16) {
    msh[tid] = m_ws[b * 16 + tid];
    lsh[tid] = l_ws[b * 16 + tid];
  }
  __syncthreads();
  float M = msh[0];
#pragma unroll
  for (int k = 1; k < 16; k++) M = fmaxf(M, msh[k]);
  float L = 0.f;
#pragma unroll
  for (int k = 0; k < 16; k++) L += lsh[k] * __expf(msh[k] - M);
  const float invL = 1.f / L;

  float2 acc = {0.f, 0.f};
#pragma unroll
  for (int k = 0; k < 16; k++) {
    float sc = __expf(msh[k] - M);
    float2 t = *(const float2*)&ck_ws[((size_t)(b * 16 + k)) * 512 + tid * 2];
    acc.x += sc * t.x; acc.y += sc * t.y;
  }
  acc.x *= invL; acc.y *= invL;
  *(float2*)&ctx[(b << 9) + tid * 2] = acc;

  float* row = w + (size_t)b * NS;
#pragma unroll
  for (int i = 0; i < 8; i++) {
    float s = row[i * 256 + tid];
    row[i * 256 + tid] = __expf(s - M) * invL;
  }
}

extern "C" void kernel_launch(void* const* d_in, const int* in_sizes, int n_in,
                              void* d_out, int out_size, void* d_ws, size_t ws_size,
                              hipStream_t stream) {
  (void)in_sizes; (void)n_in; (void)out_size; (void)ws_size;
  const float* H  = (const float*)d_in[0];
  const float* EO = (const float*)d_in[1];
  const float* W1 = (const float*)d_in[2];
  const float* b1 = (const float*)d_in[3];
  const float* W2 = (const float*)d_in[4];
  const float* b2 = (const float*)d_in[5];
  const float* V  = (const float*)d_in[6];
  // d_in[7] = bv: softmax is shift-invariant -> unused.

  float* out_ctx = (float*)d_out;            // [64*512]
  float* out_w   = (float*)d_out + NB * NE;  // [64*2048] raw scores -> weights

  char* ws = (char*)d_ws;
  unsigned short* W1p = (unsigned short*)ws;            // 512 KB
  float* cvec = (float*)(ws + 512 * 1024);              // 128 KB
  float* m_ws = (float*)(ws + 640 * 1024);              // 4 KB
  float* l_ws = (float*)(ws + 644 * 1024);              // 4 KB
  float* ck_ws = (float*)(ws + 656 * 1024);             // 2 MB

  pack_w1_kernel<<<1024, 256, 0, stream>>>(W1, W1p);
  compute_c_kernel<<<NB, 512, 0, stream>>>(H, W2, b1, b2, cvec);
  scores_ctx_kernel<<<1024, 256, 0, stream>>>(EO, W1p, cvec, V, out_w,
                                              m_ws, l_ws, ck_ws);
  combine_kernel<<<NB, 256, 0, stream>>>(m_ws, l_ws, ck_ws, out_ctx, out_w);
}

// Round 4
// 568.660 us; speedup vs baseline: 1.4510x; 1.1705x over previous
//
#include <hip/hip_runtime.h>
#include <hip/hip_bf16.h>

// ---------------------------------------------------------------------------
// Bahdanau attention, fused flash-style.  B=64, S=2048, E=D=U=512.
//  K1: pack W1 (fp32) -> bf16 in MFMA B-fragment order (ws)
//  K2: c[b,u] = H@W2 + b1 + b2   (fp32, ws)
//  K3: scores_ctx: per (b, 64-row strip), 4 waves x 16 rows:
//        afrag = 16 rows x K=512 bf16 in 64 VGPRs (fits: no spill by design)
//        B 16KB tiles DMA double-buffered in LDS (global_load_lds, 0 VGPRs)
//        score s = tanh(EO@W1 + c)·V ; strip m,l ; partial ctx from afrag
//  K4: combine 32 strips: M,L per b; context; weights = exp(s-M)/L.
// d_out layout: context [64*512] then weights [64*2048].
// ws: W1p 512K | cvec 128K | m 16K | l 16K | ck 4M   (~4.7 MB)
// ---------------------------------------------------------------------------

typedef __attribute__((ext_vector_type(8))) short bf16x8;   // 8 bf16 = 4 VGPR
typedef __attribute__((ext_vector_type(4))) float f32x4;

#define NB 64
#define NS 2048
#define NE 512
#define NU 512

// async 16B/lane global->LDS DMA: lds dest = wave-uniform base + lane*16
#define ASYNC_CP16(gsrc, ldst)                                               \
  __builtin_amdgcn_global_load_lds(                                          \
      (const __attribute__((address_space(1))) unsigned int*)(gsrc),         \
      (__attribute__((address_space(3))) unsigned int*)(ldst), 16, 0, 0)

__device__ __forceinline__ unsigned short f2bf(float f) {
  union { float f; unsigned int u; } x; x.f = f;
  unsigned int u = x.u;
  unsigned int r = (u + 0x7fffu + ((u >> 16) & 1u)) >> 16;  // RNE
  return (unsigned short)r;
}

__device__ __forceinline__ float bf2f(short s) {
  union { unsigned int u; float f; } x;
  x.u = ((unsigned int)(unsigned short)s) << 16;
  return x.f;
}

__device__ __forceinline__ float tanh_fast(float x) {
  x = fminf(fmaxf(x, -15.f), 15.f);
  float e = __expf(2.f * x);
  return 1.f - 2.f / (e + 1.f);
}

// --- K1: pack W1[k][n] (fp32 512x512) -> bf16 MFMA B-frag order:
//     W1p[(((nt*16+kt)*64 + lane)*8 + j)] = bf16(W1[kt*32+(lane>>4)*8+j][nt*16+(lane&15)])
__global__ __launch_bounds__(256) void pack_w1_kernel(
    const float* __restrict__ W1, unsigned short* __restrict__ W1p) {
  int t = blockIdx.x * 256 + threadIdx.x;
  int k = t >> 9, n = t & 511;
  int kt = k >> 5, kr = k & 31;
  int quad = kr >> 3, j = kr & 7;
  int l = (quad << 4) | (n & 15);
  int nt = n >> 4;
  int dst = ((((nt << 4) + kt) * 64 + l) << 3) + j;
  W1p[dst] = f2bf(W1[t]);
}

// --- K2: c[b][u] = sum_d H[b][d]*W2[d][u] + b1[u] + b2[u]
__global__ __launch_bounds__(512) void compute_c_kernel(
    const float* __restrict__ H, const float* __restrict__ W2,
    const float* __restrict__ b1, const float* __restrict__ b2,
    float* __restrict__ cvec) {
  const int b = blockIdx.x, u = threadIdx.x;
  __shared__ float hs[512];
  hs[u] = H[(b << 9) + u];
  __syncthreads();
  float s = 0.f;
#pragma unroll 8
  for (int d = 0; d < 512; d++) s = fmaf(hs[d], W2[(d << 9) + u], s);
  cvec[(b << 9) + u] = s + b1[u] + b2[u];
}

// --- K3: scores + softmax partials + context partials.
// grid 2048 (= 64 b * 32 strips of 64 rows), 256 thr (4 waves x 16 rows).
__global__ __launch_bounds__(256, 3) void scores_ctx_kernel(
    const float* __restrict__ EO, const unsigned short* __restrict__ W1p,
    const float* __restrict__ cvec, const float* __restrict__ V,
    float* __restrict__ scores, float* __restrict__ m_ws,
    float* __restrict__ l_ws, float* __restrict__ ck_ws) {
  __shared__ __align__(16) unsigned short Bs[2][8192];  // 2 x 16KB (1 nt tile)
  __shared__ float cs[512], vs[512];
  __shared__ float sc_l[64], p_l[64];
  __shared__ __align__(16) float cpart[4][512];
  __shared__ float m_sh;

  const int tid = threadIdx.x;
  const int b = blockIdx.x >> 5;
  const int strip = blockIdx.x & 31;
  const int s0 = strip << 6;   // *64
  const int lane = tid & 63, wave = tid >> 6;
  const int quad = lane >> 4, col = lane & 15;

  const uint4* W1p4 = (const uint4*)W1p;  // one 16KB tile = 1024 uint4

  // ---- kick off DMA of B tile 0 (nt=0); 1024 uint4 = 4 x 256 lanes
#pragma unroll
  for (int i = 0; i < 4; i++)
    ASYNC_CP16(W1p4 + i * 256 + wave * 64 + lane,
               ((char*)&Bs[0][0]) + (i * 256 + wave * 64) * 16);

  cs[tid] = cvec[(b << 9) + tid];
  cs[tid + 256] = cvec[(b << 9) + 256 + tid];
  vs[tid] = V[tid];
  vs[tid + 256] = V[256 + tid];

  // ---- A-fragments straight from global: 16 rows x K=512, fp32 -> bf16.
  //      Lane (quad,col) holds row col, k = kt*32 + quad*8 + j.  64 VGPRs.
  bf16x8 afrag[16];
  {
    const float* rp =
        EO + ((size_t)(b * NS + s0 + wave * 16 + col)) * NE + quad * 8;
#pragma unroll
    for (int kt = 0; kt < 16; kt++) {
      float4 x = *(const float4*)(rp + kt * 32);
      float4 y = *(const float4*)(rp + kt * 32 + 4);
      union { short s[8]; bf16x8 v; } u0;
      u0.s[0] = (short)f2bf(x.x); u0.s[1] = (short)f2bf(x.y);
      u0.s[2] = (short)f2bf(x.z); u0.s[3] = (short)f2bf(x.w);
      u0.s[4] = (short)f2bf(y.x); u0.s[5] = (short)f2bf(y.y);
      u0.s[6] = (short)f2bf(y.z); u0.s[7] = (short)f2bf(y.w);
      afrag[kt] = u0.v;
    }
  }

  __syncthreads();  // drains DMA vmcnt -> tile 0 ready

  float sacc[4] = {0.f, 0.f, 0.f, 0.f};

  for (int nt = 0; nt < 32; nt++) {
    const int cur = nt & 1;
    // DMA-prefetch next 16KB B tile into the other buffer (overlaps MFMAs)
    if (nt < 31) {
#pragma unroll
      for (int i = 0; i < 4; i++)
        ASYNC_CP16(W1p4 + (nt + 1) * 1024 + i * 256 + wave * 64 + lane,
                   ((char*)&Bs[cur ^ 1][0]) + (i * 256 + wave * 64) * 16);
    }
    f32x4 acc = {0.f, 0.f, 0.f, 0.f};
    const bf16x8* bp = (const bf16x8*)&Bs[cur][0];
#pragma unroll
    for (int kt = 0; kt < 16; kt++) {
      bf16x8 bfr = bp[kt * 64 + lane];
      acc = __builtin_amdgcn_mfma_f32_16x16x32_bf16(afrag[kt], bfr, acc, 0, 0, 0);
    }
    // fused epilogue: score partial += tanh(acc + c[u]) * V[u]
    int u = (nt << 4) + col;
    float cu = cs[u], vu = vs[u];
#pragma unroll
    for (int r = 0; r < 4; r++)
      sacc[r] += tanh_fast(acc[r] + cu) * vu;
    __syncthreads();  // all reads of cur done + next tile's DMA drained
  }

  // ---- reduce scores over the 16 col-lanes of each quad-group
#pragma unroll
  for (int m = 1; m < 16; m <<= 1)
#pragma unroll
    for (int r = 0; r < 4; r++)
      sacc[r] += __shfl_xor(sacc[r], m, 64);

  if (col == 0) {
#pragma unroll
    for (int r = 0; r < 4; r++) {
      int row = wave * 16 + quad * 4 + r;   // C/D: row = quad*4 + reg
      sc_l[row] = sacc[r];
      scores[(size_t)b * NS + s0 + row] = sacc[r];  // raw scores
    }
  }
  __syncthreads();

  // ---- strip max + l over the 64 rows (wave 0)
  if (wave == 0) {
    float m0 = sc_l[lane];
#pragma unroll
    for (int off = 32; off; off >>= 1) m0 = fmaxf(m0, __shfl_xor(m0, off, 64));
    if (lane == 0) m_sh = m0;
    float p = __expf(sc_l[lane] - m0);
    p_l[lane] = p;
#pragma unroll
    for (int off = 32; off; off >>= 1) p += __shfl_xor(p, off, 64);
    if (lane == 0) {
      m_ws[b * 32 + strip] = m0;
      l_ws[b * 32 + strip] = p;
    }
  }
  __syncthreads();

  // ---- context partials from register-resident bf16 EO fragments.
  // lane holds row (wave*16 + col), e = kt*32 + quad*8 + j.
  const float p0 = p_l[wave * 16 + col];
#pragma unroll
  for (int kt = 0; kt < 16; kt++) {
    float v[8];
#pragma unroll
    for (int j = 0; j < 8; j++) v[j] = p0 * bf2f(afrag[kt][j]);
#pragma unroll
    for (int m = 1; m < 16; m <<= 1)
#pragma unroll
      for (int j = 0; j < 8; j++) v[j] += __shfl_xor(v[j], m, 64);
    if (col == 0) {
      float* dst = &cpart[wave][kt * 32 + quad * 8];
      *(float4*)dst = make_float4(v[0], v[1], v[2], v[3]);
      *(float4*)(dst + 4) = make_float4(v[4], v[5], v[6], v[7]);
    }
  }
  __syncthreads();

  // ---- fold 4 wave-partials, write strip context partial to ws
  {
    float2 s = {0.f, 0.f};
#pragma unroll
    for (int w = 0; w < 4; w++) {
      float2 t = *(const float2*)&cpart[w][tid * 2];
      s.x += t.x; s.y += t.y;
    }
    *(float2*)&ck_ws[((size_t)(b * 32 + strip)) * 512 + tid * 2] = s;
  }
}

// --- K4: combine 32 strips: context + normalized weights.  64 blocks x 256.
__global__ __launch_bounds__(256) void combine_kernel(
    const float* __restrict__ m_ws, const float* __restrict__ l_ws,
    const float* __restrict__ ck_ws, float* __restrict__ ctx,
    float* __restrict__ w /* raw scores in, weights out */) {
  const int b = blockIdx.x, tid = threadIdx.x;
  __shared__ float msh[32], lsh[32];
  if (tid < 32) {
    msh[tid] = m_ws[b * 32 + tid];
    lsh[tid] = l_ws[b * 32 + tid];
  }
  __syncthreads();
  float M = msh[0];
#pragma unroll
  for (int k = 1; k < 32; k++) M = fmaxf(M, msh[k]);
  float L = 0.f;
#pragma unroll
  for (int k = 0; k < 32; k++) L += lsh[k] * __expf(msh[k] - M);
  const float invL = 1.f / L;

  float2 acc = {0.f, 0.f};
#pragma unroll
  for (int k = 0; k < 32; k++) {
    float sc = __expf(msh[k] - M);
    float2 t = *(const float2*)&ck_ws[((size_t)(b * 32 + k)) * 512 + tid * 2];
    acc.x += sc * t.x; acc.y += sc * t.y;
  }
  acc.x *= invL; acc.y *= invL;
  *(float2*)&ctx[(b << 9) + tid * 2] = acc;

  float* row = w + (size_t)b * NS;
#pragma unroll
  for (int i = 0; i < 8; i++) {
    float s = row[i * 256 + tid];
    row[i * 256 + tid] = __expf(s - M) * invL;
  }
}

extern "C" void kernel_launch(void* const* d_in, const int* in_sizes, int n_in,
                              void* d_out, int out_size, void* d_ws, size_t ws_size,
                              hipStream_t stream) {
  (void)in_sizes; (void)n_in; (void)out_size; (void)ws_size;
  const float* H  = (const float*)d_in[0];
  const float* EO = (const float*)d_in[1];
  const float* W1 = (const float*)d_in[2];
  const float* b1 = (const float*)d_in[3];
  const float* W2 = (const float*)d_in[4];
  const float* b2 = (const float*)d_in[5];
  const float* V  = (const float*)d_in[6];
  // d_in[7] = bv: softmax is shift-invariant -> unused.

  float* out_ctx = (float*)d_out;            // [64*512]
  float* out_w   = (float*)d_out + NB * NE;  // [64*2048] raw scores -> weights

  char* ws = (char*)d_ws;
  unsigned short* W1p = (unsigned short*)ws;            // 512 KB
  float* cvec = (float*)(ws + 512 * 1024);              // 128 KB
  float* m_ws = (float*)(ws + 640 * 1024);              // 8 KB
  float* l_ws = (float*)(ws + 656 * 1024);              // 8 KB
  float* ck_ws = (float*)(ws + 672 * 1024);             // 4 MB

  pack_w1_kernel<<<1024, 256, 0, stream>>>(W1, W1p);
  compute_c_kernel<<<NB, 512, 0, stream>>>(H, W2, b1, b2, cvec);
  scores_ctx_kernel<<<2048, 256, 0, stream>>>(EO, W1p, cvec, V, out_w,
                                              m_ws, l_ws, ck_ws);
  combine_kernel<<<NB, 256, 0, stream>>>(m_ws, l_ws, ck_ws, out_ctx, out_w);
}

// Round 5
// 556.776 us; speedup vs baseline: 1.4820x; 1.0213x over previous
//
#include <hip/hip_runtime.h>
#include <hip/hip_bf16.h>

// ---------------------------------------------------------------------------
// Bahdanau attention, fused flash-style.  B=64, S=2048, E=D=U=512.
//  K1: pack W1 (fp32) -> bf16 in MFMA B-fragment order (ws)
//  K2: c[b,u] = H@W2 + b1 + b2   (fp32, ws)
//  K3: scores_ctx: per (b, 64-row strip), 4 waves x 16 rows:
//        afrag = 16 rows x K=512 bf16 in 64 VGPRs.
//        NOTE __launch_bounds__(256,2): with MFMA the allocator splits the
//        unified VGPR file ~half arch / half acc; (256,3) capped arch at ~85
//        and spilled ~19 regs -> 200 MB scratch traffic (R4 evidence).
//        (256,2) gives arch ~128 >= ~104 needed -> no spill.
//        B 16KB tiles DMA double-buffered in LDS (global_load_lds, 0 VGPRs)
//        score s = tanh(EO@W1 + c)·V ; strip m,l ; partial ctx from afrag
//  K4: combine 32 strips: M,L per b; context; weights = exp(s-M)/L.
// d_out layout: context [64*512] then weights [64*2048].
// ws: W1p 512K | cvec 128K | m 8K | l 8K | ck 4M   (~4.7 MB)
// ---------------------------------------------------------------------------

typedef __attribute__((ext_vector_type(8))) short bf16x8;   // 8 bf16 = 4 VGPR
typedef __attribute__((ext_vector_type(4))) float f32x4;

#define NB 64
#define NS 2048
#define NE 512
#define NU 512

// async 16B/lane global->LDS DMA: lds dest = wave-uniform base + lane*16
#define ASYNC_CP16(gsrc, ldst)                                               \
  __builtin_amdgcn_global_load_lds(                                          \
      (const __attribute__((address_space(1))) unsigned int*)(gsrc),         \
      (__attribute__((address_space(3))) unsigned int*)(ldst), 16, 0, 0)

__device__ __forceinline__ unsigned short f2bf(float f) {
  union { float f; unsigned int u; } x; x.f = f;
  unsigned int u = x.u;
  unsigned int r = (u + 0x7fffu + ((u >> 16) & 1u)) >> 16;  // RNE
  return (unsigned short)r;
}

__device__ __forceinline__ float bf2f(short s) {
  union { unsigned int u; float f; } x;
  x.u = ((unsigned int)(unsigned short)s) << 16;
  return x.f;
}

__device__ __forceinline__ float tanh_fast(float x) {
  x = fminf(fmaxf(x, -15.f), 15.f);
  float e = __expf(2.f * x);
  return 1.f - 2.f / (e + 1.f);
}

// --- K1: pack W1[k][n] (fp32 512x512) -> bf16 MFMA B-frag order:
//     W1p[(((nt*16+kt)*64 + lane)*8 + j)] = bf16(W1[kt*32+(lane>>4)*8+j][nt*16+(lane&15)])
__global__ __launch_bounds__(256) void pack_w1_kernel(
    const float* __restrict__ W1, unsigned short* __restrict__ W1p) {
  int t = blockIdx.x * 256 + threadIdx.x;
  int k = t >> 9, n = t & 511;
  int kt = k >> 5, kr = k & 31;
  int quad = kr >> 3, j = kr & 7;
  int l = (quad << 4) | (n & 15);
  int nt = n >> 4;
  int dst = ((((nt << 4) + kt) * 64 + l) << 3) + j;
  W1p[dst] = f2bf(W1[t]);
}

// --- K2: c[b][u] = sum_d H[b][d]*W2[d][u] + b1[u] + b2[u]
__global__ __launch_bounds__(512) void compute_c_kernel(
    const float* __restrict__ H, const float* __restrict__ W2,
    const float* __restrict__ b1, const float* __restrict__ b2,
    float* __restrict__ cvec) {
  const int b = blockIdx.x, u = threadIdx.x;
  __shared__ float hs[512];
  hs[u] = H[(b << 9) + u];
  __syncthreads();
  float s = 0.f;
#pragma unroll 8
  for (int d = 0; d < 512; d++) s = fmaf(hs[d], W2[(d << 9) + u], s);
  cvec[(b << 9) + u] = s + b1[u] + b2[u];
}

// --- K3: scores + softmax partials + context partials.
// grid 2048 (= 64 b * 32 strips of 64 rows), 256 thr (4 waves x 16 rows).
__global__ __launch_bounds__(256, 2) void scores_ctx_kernel(
    const float* __restrict__ EO, const unsigned short* __restrict__ W1p,
    const float* __restrict__ cvec, const float* __restrict__ V,
    float* __restrict__ scores, float* __restrict__ m_ws,
    float* __restrict__ l_ws, float* __restrict__ ck_ws) {
  __shared__ __align__(16) unsigned short Bs[2][8192];  // 2 x 16KB (1 nt tile)
  __shared__ float cs[512], vs[512];
  __shared__ float sc_l[64], p_l[64];
  __shared__ __align__(16) float cpart[4][512];
  __shared__ float m_sh;

  const int tid = threadIdx.x;
  const int b = blockIdx.x >> 5;
  const int strip = blockIdx.x & 31;
  const int s0 = strip << 6;   // *64
  const int lane = tid & 63, wave = tid >> 6;
  const int quad = lane >> 4, col = lane & 15;

  const uint4* W1p4 = (const uint4*)W1p;  // one 16KB tile = 1024 uint4

  // ---- kick off DMA of B tile 0 (nt=0); 1024 uint4 = 4 x 256 lanes
#pragma unroll
  for (int i = 0; i < 4; i++)
    ASYNC_CP16(W1p4 + i * 256 + wave * 64 + lane,
               ((char*)&Bs[0][0]) + (i * 256 + wave * 64) * 16);

  cs[tid] = cvec[(b << 9) + tid];
  cs[tid + 256] = cvec[(b << 9) + 256 + tid];
  vs[tid] = V[tid];
  vs[tid + 256] = V[256 + tid];

  // ---- A-fragments straight from global: 16 rows x K=512, fp32 -> bf16.
  //      Lane (quad,col) holds row col, k = kt*32 + quad*8 + j.  64 VGPRs.
  bf16x8 afrag[16];
  {
    const float* rp =
        EO + ((size_t)(b * NS + s0 + wave * 16 + col)) * NE + quad * 8;
#pragma unroll
    for (int kt = 0; kt < 16; kt++) {
      float4 x = *(const float4*)(rp + kt * 32);
      float4 y = *(const float4*)(rp + kt * 32 + 4);
      union { short s[8]; bf16x8 v; } u0;
      u0.s[0] = (short)f2bf(x.x); u0.s[1] = (short)f2bf(x.y);
      u0.s[2] = (short)f2bf(x.z); u0.s[3] = (short)f2bf(x.w);
      u0.s[4] = (short)f2bf(y.x); u0.s[5] = (short)f2bf(y.y);
      u0.s[6] = (short)f2bf(y.z); u0.s[7] = (short)f2bf(y.w);
      afrag[kt] = u0.v;
    }
  }

  __syncthreads();  // drains DMA vmcnt -> tile 0 ready

  float sacc[4] = {0.f, 0.f, 0.f, 0.f};

  for (int nt = 0; nt < 32; nt++) {
    const int cur = nt & 1;
    // DMA-prefetch next 16KB B tile into the other buffer (overlaps MFMAs)
    if (nt < 31) {
#pragma unroll
      for (int i = 0; i < 4; i++)
        ASYNC_CP16(W1p4 + (nt + 1) * 1024 + i * 256 + wave * 64 + lane,
                   ((char*)&Bs[cur ^ 1][0]) + (i * 256 + wave * 64) * 16);
    }
    f32x4 acc = {0.f, 0.f, 0.f, 0.f};
    const bf16x8* bp = (const bf16x8*)&Bs[cur][0];
#pragma unroll
    for (int kt = 0; kt < 16; kt++) {
      bf16x8 bfr = bp[kt * 64 + lane];
      acc = __builtin_amdgcn_mfma_f32_16x16x32_bf16(afrag[kt], bfr, acc, 0, 0, 0);
    }
    // fused epilogue: score partial += tanh(acc + c[u]) * V[u]
    int u = (nt << 4) + col;
    float cu = cs[u], vu = vs[u];
#pragma unroll
    for (int r = 0; r < 4; r++)
      sacc[r] += tanh_fast(acc[r] + cu) * vu;
    __syncthreads();  // all reads of cur done + next tile's DMA drained
  }

  // ---- reduce scores over the 16 col-lanes of each quad-group
#pragma unroll
  for (int m = 1; m < 16; m <<= 1)
#pragma unroll
    for (int r = 0; r < 4; r++)
      sacc[r] += __shfl_xor(sacc[r], m, 64);

  if (col == 0) {
#pragma unroll
    for (int r = 0; r < 4; r++) {
      int row = wave * 16 + quad * 4 + r;   // C/D: row = quad*4 + reg
      sc_l[row] = sacc[r];
      scores[(size_t)b * NS + s0 + row] = sacc[r];  // raw scores
    }
  }
  __syncthreads();

  // ---- strip max + l over the 64 rows (wave 0)
  if (wave == 0) {
    float m0 = sc_l[lane];
#pragma unroll
    for (int off = 32; off; off >>= 1) m0 = fmaxf(m0, __shfl_xor(m0, off, 64));
    if (lane == 0) m_sh = m0;
    float p = __expf(sc_l[lane] - m0);
    p_l[lane] = p;
#pragma unroll
    for (int off = 32; off; off >>= 1) p += __shfl_xor(p, off, 64);
    if (lane == 0) {
      m_ws[b * 32 + strip] = m0;
      l_ws[b * 32 + strip] = p;
    }
  }
  __syncthreads();

  // ---- context partials from register-resident bf16 EO fragments.
  // lane holds row (wave*16 + col), e = kt*32 + quad*8 + j.
  const float p0 = p_l[wave * 16 + col];
#pragma unroll
  for (int kt = 0; kt < 16; kt++) {
    float v[8];
#pragma unroll
    for (int j = 0; j < 8; j++) v[j] = p0 * bf2f(afrag[kt][j]);
#pragma unroll
    for (int m = 1; m < 16; m <<= 1)
#pragma unroll
      for (int j = 0; j < 8; j++) v[j] += __shfl_xor(v[j], m, 64);
    if (col == 0) {
      float* dst = &cpart[wave][kt * 32 + quad * 8];
      *(float4*)dst = make_float4(v[0], v[1], v[2], v[3]);
      *(float4*)(dst + 4) = make_float4(v[4], v[5], v[6], v[7]);
    }
  }
  __syncthreads();

  // ---- fold 4 wave-partials, write strip context partial to ws
  {
    float2 s = {0.f, 0.f};
#pragma unroll
    for (int w = 0; w < 4; w++) {
      float2 t = *(const float2*)&cpart[w][tid * 2];
      s.x += t.x; s.y += t.y;
    }
    *(float2*)&ck_ws[((size_t)(b * 32 + strip)) * 512 + tid * 2] = s;
  }
}

// --- K4: combine 32 strips: context + normalized weights.  64 blocks x 256.
__global__ __launch_bounds__(256) void combine_kernel(
    const float* __restrict__ m_ws, const float* __restrict__ l_ws,
    const float* __restrict__ ck_ws, float* __restrict__ ctx,
    float* __restrict__ w /* raw scores in, weights out */) {
  const int b = blockIdx.x, tid = threadIdx.x;
  __shared__ float msh[32], lsh[32];
  if (tid < 32) {
    msh[tid] = m_ws[b * 32 + tid];
    lsh[tid] = l_ws[b * 32 + tid];
  }
  __syncthreads();
  float M = msh[0];
#pragma unroll
  for (int k = 1; k < 32; k++) M = fmaxf(M, msh[k]);
  float L = 0.f;
#pragma unroll
  for (int k = 0; k < 32; k++) L += lsh[k] * __expf(msh[k] - M);
  const float invL = 1.f / L;

  float2 acc = {0.f, 0.f};
#pragma unroll
  for (int k = 0; k < 32; k++) {
    float sc = __expf(msh[k] - M);
    float2 t = *(const float2*)&ck_ws[((size_t)(b * 32 + k)) * 512 + tid * 2];
    acc.x += sc * t.x; acc.y += sc * t.y;
  }
  acc.x *= invL; acc.y *= invL;
  *(float2*)&ctx[(b << 9) + tid * 2] = acc;

  float* row = w + (size_t)b * NS;
#pragma unroll
  for (int i = 0; i < 8; i++) {
    float s = row[i * 256 + tid];
    row[i * 256 + tid] = __expf(s - M) * invL;
  }
}

extern "C" void kernel_launch(void* const* d_in, const int* in_sizes, int n_in,
                              void* d_out, int out_size, void* d_ws, size_t ws_size,
                              hipStream_t stream) {
  (void)in_sizes; (void)n_in; (void)out_size; (void)ws_size;
  const float* H  = (const float*)d_in[0];
  const float* EO = (const float*)d_in[1];
  const float* W1 = (const float*)d_in[2];
  const float* b1 = (const float*)d_in[3];
  const float* W2 = (const float*)d_in[4];
  const float* b2 = (const float*)d_in[5];
  const float* V  = (const float*)d_in[6];
  // d_in[7] = bv: softmax is shift-invariant -> unused.

  float* out_ctx = (float*)d_out;            // [64*512]
  float* out_w   = (float*)d_out + NB * NE;  // [64*2048] raw scores -> weights

  char* ws = (char*)d_ws;
  unsigned short* W1p = (unsigned short*)ws;            // 512 KB
  float* cvec = (float*)(ws + 512 * 1024);              // 128 KB
  float* m_ws = (float*)(ws + 640 * 1024);              // 8 KB
  float* l_ws = (float*)(ws + 656 * 1024);              // 8 KB
  float* ck_ws = (float*)(ws + 672 * 1024);             // 4 MB

  pack_w1_kernel<<<1024, 256, 0, stream>>>(W1, W1p);
  compute_c_kernel<<<NB, 512, 0, stream>>>(H, W2, b1, b2, cvec);
  scores_ctx_kernel<<<2048, 256, 0, stream>>>(EO, W1p, cvec, V, out_w,
                                              m_ws, l_ws, ck_ws);
  combine_kernel<<<NB, 256, 0, stream>>>(m_ws, l_ws, ck_ws, out_ctx, out_w);
}